// Round 9
// baseline (104.927 us; speedup 1.0000x reference)
//
#include <hip/hip_runtime.h>
#include <hip/hip_bf16.h>

#define N_IN   5023
#define B_SZ   64
#define H_DIM  256
#define NPAD   5120
#define NBD    192          // B_SZ * 3
#define SPLITZ 40           // gemm3 split-K slices, 128-wide chunks
#define OUT_ELEMS (B_SZ * N_IN * 3)   // 964416

typedef short bf16x8 __attribute__((ext_vector_type(8)));
typedef float f32x4  __attribute__((ext_vector_type(4)));
typedef int   i32x4  __attribute__((ext_vector_type(4)));
typedef int   i32x8  __attribute__((ext_vector_type(8)));

__device__ inline void async_copy16(const void* g, void* l) {
    __builtin_amdgcn_global_load_lds(
        (const __attribute__((address_space(1))) unsigned int*)g,
        (__attribute__((address_space(3))) unsigned int*)l,
        16, 0, 0);
}

__device__ inline unsigned char to_fp8(float v) {
    int p = __builtin_amdgcn_cvt_pk_fp8_f32(v, 0.0f, 0, false);
    return (unsigned char)(p & 0xFF);
}

// ---- conv_all (scalar epilogue — measured best):
//      z=0: key_w[i][h] -> k8 fp8 [5120][256] + keyT bf16 [256][5120]
//      z=1: query_w[h][o] -> q8 fp8 [5120][256] + qtb bf16 [5120][256] (*1/16)
//      q8/k8 hold UNSCALED values (sigma 0.0625, e4m3 normal range).
//      Also zeroes l1 (z=0 blocks). ----
__global__ void conv_all(const float* __restrict__ kw, const float* __restrict__ qw,
                         unsigned char* __restrict__ k8, short* __restrict__ keyT,
                         unsigned char* __restrict__ q8, short* __restrict__ qtb,
                         float* __restrict__ l1) {
    __shared__ float tile[32][33];
    const int hb = blockIdx.x * 32;      // 8 tiles over H
    const int nb = blockIdx.y * 32;      // 160 tiles over NPAD
    const int tx = threadIdx.x;          // 32
    const int ty = threadIdx.y;          // 8
    if (blockIdx.z == 0) {
        // key: read [i][h] coalesced; k8 straight; keyT transposed.
        for (int j = 0; j < 32; j += 8) {
            int i = nb + ty + j;
            int h = hb + tx;
            float v = (i < N_IN) ? kw[(size_t)i * H_DIM + h] : 0.0f;
            tile[ty + j][tx] = v;
            k8[(size_t)i * H_DIM + h] = to_fp8(v);
        }
        __syncthreads();
        __hip_bfloat16* kt = (__hip_bfloat16*)keyT;
        for (int j = 0; j < 32; j += 8) {
            int h = hb + ty + j;
            int i = nb + tx;
            kt[(size_t)h * NPAD + i] = __float2bfloat16(tile[tx][ty + j]);
        }
        if (blockIdx.x == 0 && ty == 0) l1[nb + tx] = 0.0f;
    } else {
        // query: read [h][o] coalesced; q8 + qtb from transposed side.
        for (int j = 0; j < 32; j += 8) {
            int h = hb + ty + j;
            int o = nb + tx;
            tile[ty + j][tx] = (o < N_IN) ? qw[(size_t)h * N_IN + o] : 0.0f;
        }
        __syncthreads();
        __hip_bfloat16* qt = (__hip_bfloat16*)qtb;
        for (int j = 0; j < 32; j += 8) {
            int o = nb + ty + j;
            int h = hb + tx;
            float v = tile[tx][ty + j];
            qt[(size_t)o * H_DIM + h] = __float2bfloat16(v * 0.0625f);
            q8[(size_t)o * H_DIM + h] = to_fp8(v);
        }
    }
}

// ---- GEMM_L1 (MX-fp8, K=128 per MFMA): l1[i] = sum_o |sum_h q8[o][h]*k8[i][h]|
//      (unscaled by 16^2; folded out downstream). M=N=5120, K=256, tile 128x128,
//      BK=128 (2 rounds), LDS 2x16KB, XOR-swizzled 16B slots (key = row&7).
//      mfma_scale_f32_16x16x128_f8f6f4 with unit E8M0 scales (0x7F bytes) is
//      numerically identical to the non-scaled fp8 path at 2x the rate. ----
__launch_bounds__(256)
__global__ void gemm_l1(const unsigned char* __restrict__ q8,
                        const unsigned char* __restrict__ k8,
                        float* __restrict__ l1) {
    __shared__ unsigned char As8[128 * 128];   // 16 KB
    __shared__ unsigned char Bs8[128 * 128];   // 16 KB
    const int bm = blockIdx.x, bn = blockIdx.y;
    const int tid = threadIdx.x, lane = tid & 63, wid = tid >> 6;
    const int wave_m = wid >> 1, wave_n = wid & 1;
    const int r = lane >> 3;          // 0..7 row within chunk
    const int s = lane & 7;           // 0..7 16B slot
    const int quad = lane >> 4, cit = lane & 15;
    const int xk = cit & 7;           // fragment xor key (= row & 7)

    f32x4 acc[4][4];
    const f32x4 zf = {0.f, 0.f, 0.f, 0.f};
    for (int a = 0; a < 4; ++a)
        for (int b = 0; b < 4; ++b) acc[a][b] = zf;

    // lane's K-slice for the K=128 MFMA: bytes [quad*32, quad*32+32) of its row,
    // i.e. 16B groups g0=2*quad, g1=2*quad+1 (XOR-swizzled in LDS).
    const int g0 = (2 * quad) ^ xk;
    const int g1 = (2 * quad + 1) ^ xk;

    for (int kb = 0; kb < H_DIM; kb += 128) {
        __syncthreads();
        const int koff = kb + ((s ^ r) << 4);   // swizzled global k-group
        for (int c = 0; c < 4; ++c) {
            int q = wid * 4 + c;                // 1KB chunk 0..15 (8 rows each)
            int row = q * 8 + r;
            async_copy16(q8 + (size_t)(bm * 128 + row) * H_DIM + koff, As8 + q * 1024);
            async_copy16(k8 + (size_t)(bn * 128 + row) * H_DIM + koff, Bs8 + q * 1024);
        }
        __syncthreads();
        // A fragments: 4 rows of 32B each (2 x ds_read_b128)
        i32x8 af[4];
        for (int t = 0; t < 4; ++t) {
            const unsigned char* pa = As8 + (wave_m * 64 + t * 16 + cit) * 128;
            i32x4 lo = *(const i32x4*)(pa + (g0 << 4));
            i32x4 hi = *(const i32x4*)(pa + (g1 << 4));
            af[t] = __builtin_shufflevector(lo, hi, 0, 1, 2, 3, 4, 5, 6, 7);
        }
        // B fragment per output column, then 4 MFMAs down the column
        for (int tn = 0; tn < 4; ++tn) {
            const unsigned char* pb = Bs8 + (wave_n * 64 + tn * 16 + cit) * 128;
            i32x4 lo = *(const i32x4*)(pb + (g0 << 4));
            i32x4 hi = *(const i32x4*)(pb + (g1 << 4));
            i32x8 bf = __builtin_shufflevector(lo, hi, 0, 1, 2, 3, 4, 5, 6, 7);
            for (int tm = 0; tm < 4; ++tm)
                acc[tm][tn] = __builtin_amdgcn_mfma_scale_f32_16x16x128_f8f6f4(
                    af[tm], bf, acc[tm][tn], 0, 0,   // cbsz=fp8(e4m3), blgp=fp8(e4m3)
                    0, 0x7F7F7F7F,                   // A scales: E8M0 127 -> 2^0
                    0, 0x7F7F7F7F);                  // B scales: E8M0 127 -> 2^0
        }
    }

    for (int tn = 0; tn < 4; ++tn) {
        int ig = bn * 128 + wave_n * 64 + tn * 16 + cit;   // column i
        float p = 0.0f;
        for (int tm = 0; tm < 4; ++tm) {
            f32x4 c = acc[tm][tn];
            p += fabsf(c.x) + fabsf(c.y) + fabsf(c.z) + fabsf(c.w);
        }
        p += __shfl_xor(p, 16);
        p += __shfl_xor(p, 32);
        if (quad == 0) atomicAdd(&l1[ig], p);
    }
}

// ---- build_vmat: vm[b*3+e][i] = bf16((sum_d x[b,i,d]*vw[e,d]) / max(l1[i]/16,eps))
//      [192][5120] bf16. 1280 blocks; each thread: 4 independent loads, 3 stores,
//      one latency exposure. Pad region i>=N_IN written 0.
//      Also zeroes T32 (y==0 slice: 64 blocks x 256 thr x 3 = 49152). ----
__launch_bounds__(256)
__global__ void build_vmat(const float* __restrict__ x, const float* __restrict__ vw,
                           const float* __restrict__ l1, short* __restrict__ vm,
                           float* __restrict__ T32) {
    const int b = blockIdx.x;               // 64
    const int i = blockIdx.y * 256 + threadIdx.x;   // < 5120
    if (blockIdx.y == 0) {
        int idx = (blockIdx.x * 256 + threadIdx.x) * 3;
        T32[idx + 0] = 0.0f;
        T32[idx + 1] = 0.0f;
        T32[idx + 2] = 0.0f;
    }
    const bool ok = (i < N_IN);
    float x0 = 0.f, x1 = 0.f, x2 = 0.f, rcp = 0.f;
    if (ok) {
        const float* xp = x + ((size_t)b * N_IN + i) * 3;
        x0 = xp[0]; x1 = xp[1]; x2 = xp[2];
        rcp = 1.0f / fmaxf(l1[i] * 0.0625f, 1e-12f);
    }
    __hip_bfloat16* v = (__hip_bfloat16*)vm;
    v[(size_t)(b * 3 + 0) * NPAD + i] = __float2bfloat16((x0 * vw[0] + x1 * vw[1] + x2 * vw[2]) * rcp);
    v[(size_t)(b * 3 + 1) * NPAD + i] = __float2bfloat16((x0 * vw[3] + x1 * vw[4] + x2 * vw[5]) * rcp);
    v[(size_t)(b * 3 + 2) * NPAD + i] = __float2bfloat16((x0 * vw[6] + x1 * vw[7] + x2 * vw[8]) * rcp);
}

// ---- GEMM3 (pure staged GEMM, K=128/block, atomic split-K): T32[bd][h] +=
//      sum_{i in 128-chunk} vm[bd][i] * keyT[h][i]. Grid (8 h-tiles of 32, 40 z)
//      = 320 blocks. Waves 2x2: wave tile 96x16. Both K-halves staged up-front
//      (57 KB LDS, 14 copies/thread in flight, single barrier), 24 MFMAs/wave.
//      Epilogue: f32 atomicAdd into L2-resident T32 (196 KB) — no part2. ----
__launch_bounds__(256)
__global__ void gemm3_f(const short* __restrict__ vm, const short* __restrict__ keyT,
                        float* __restrict__ T32) {
    __shared__ short As[2][NBD * 64];  // 2 x 24,576 B (i-halves)
    __shared__ short Bs[2][32 * 64];   // 2 x 4,096 B
    const int bh = blockIdx.x;         // h tile (8 x 32)
    const int z  = blockIdx.y;         // i chunk (40 x 128)
    const int tid = threadIdx.x, lane = tid & 63, wid = tid >> 6;
    const int wave_m = wid >> 1, wave_n = wid & 1;
    const int rr = lane >> 3, ss = lane & 7;
    const int quad = lane >> 4, cit = lane & 15;
    const int xk = cit & 7;

    for (int hf = 0; hf < 2; ++hf) {
        const int koff = z * 128 + hf * 64 + ((ss ^ rr) << 3);  // pre-swizzled slot
        for (int c = 0; c < 6; ++c) {             // As: 24 chunks per half
            int q = wid * 6 + c;
            int row = q * 8 + rr;                 // bd 0..191
            async_copy16(vm + (size_t)row * NPAD + koff, As[hf] + q * 512);
        }
        {                                          // Bs: 4 chunks per half
            int row = wid * 8 + rr;               // h local 0..31
            async_copy16(keyT + (size_t)(bh * 32 + row) * NPAD + koff, Bs[hf] + wid * 512);
        }
    }
    __syncthreads();

    f32x4 acc[6];
    const f32x4 zf = {0.f, 0.f, 0.f, 0.f};
    for (int a = 0; a < 6; ++a) acc[a] = zf;

    for (int hf = 0; hf < 2; ++hf) {
        for (int kk = 0; kk < 64; kk += 32) {
            bf16x8 af[6], bf;
            int g = (kk >> 3) + quad;
            int slot = (g ^ xk) << 3;             // row&7 == cit&7 for all rows used
            for (int t = 0; t < 6; ++t) {
                int row = wave_m * 96 + t * 16 + cit;
                af[t] = *(const bf16x8*)(As[hf] + row * 64 + slot);
            }
            {
                int row = wave_n * 16 + cit;
                bf = *(const bf16x8*)(Bs[hf] + row * 64 + slot);
            }
            for (int tm = 0; tm < 6; ++tm)
                acc[tm] = __builtin_amdgcn_mfma_f32_16x16x32_bf16(
                    af[tm], bf, acc[tm], 0, 0, 0);
        }
    }

    const int h = bh * 32 + wave_n * 16 + cit;
    for (int tm = 0; tm < 6; ++tm) {
        int bd0 = wave_m * 96 + tm * 16 + quad * 4;
        f32x4 c = acc[tm];
        for (int r2 = 0; r2 < 4; ++r2)
            atomicAdd(&T32[(size_t)(bd0 + r2) * H_DIM + h], c[r2]);
    }
}

// ---- cvt_T: T[idx] = bf16(T32[idx]); 49152 elems, f32x4 in / short4 out. ----
__global__ void cvt_T(const float* __restrict__ T32, short* __restrict__ T) {
    int i4 = blockIdx.x * 256 + threadIdx.x;      // < 12288
    f32x4 v = ((const f32x4*)T32)[i4];
    union { __hip_bfloat16 b; short u; } c0, c1, c2, c3;
    c0.b = __float2bfloat16(v.x);
    c1.b = __float2bfloat16(v.y);
    c2.b = __float2bfloat16(v.z);
    c3.b = __float2bfloat16(v.w);
    short4 s; s.x = c0.u; s.y = c1.u; s.z = c2.u; s.w = c3.u;
    ((short4*)T)[i4] = s;
}

// ---- GEMM4: y[o][bd] = sum_h qt[o][h] * T[bd][h]; out via LDS transpose.
//      M-tile 32 -> 160 blocks. Waves 2x2: wave tile 16x96. XOR-swizzled LDS. ----
#define CS_PITCH 196
__launch_bounds__(256)
__global__ void gemm4(const short* __restrict__ qt, const short* __restrict__ T,
                      float* __restrict__ out) {
    __shared__ __align__(16) char smem[28672];   // staging 28KB / CS 25KB union
    short* As = (short*)smem;                    // 32 x 64 (4 KB, swizzled)
    short* Bs = (short*)(smem + 4096);           // 192 x 64 (24 KB, swizzled)
    const int bm = blockIdx.x;                   // 160
    const int tid = threadIdx.x, lane = tid & 63, wid = tid >> 6;
    const int wave_m = wid >> 1, wave_n = wid & 1;
    const int rr = lane >> 3, ss = lane & 7;
    const int quad = lane >> 4, cit = lane & 15;

    f32x4 acc[6];
    const f32x4 zf = {0.f, 0.f, 0.f, 0.f};
    for (int b = 0; b < 6; ++b) acc[b] = zf;

    for (int kb = 0; kb < H_DIM; kb += 64) {
        __syncthreads();
        const int koff = kb + ((ss ^ (rr & 7)) << 3);
        {   // As: 4 chunks, one per wave
            int row = wid * 8 + rr;              // 0..31
            async_copy16(qt + (size_t)(bm * 32 + row) * H_DIM + koff, As + wid * 512);
        }
        for (int c = 0; c < 6; ++c) {            // Bs: 24 chunks
            int q = wid * 6 + c;
            int row = q * 8 + rr;                // 0..191
            async_copy16(T + (size_t)row * H_DIM + koff, Bs + q * 512);
        }
        __syncthreads();
        for (int kk = 0; kk < 64; kk += 32) {
            bf16x8 af, bf[6];
            int g = (kk >> 3) + quad;
            int slot = (g ^ (cit & 7)) << 3;
            {
                int row = wave_m * 16 + cit;
                af = *(const bf16x8*)(As + row * 64 + slot);
            }
            for (int t = 0; t < 6; ++t) {
                int row = wave_n * 96 + t * 16 + cit;
                bf[t] = *(const bf16x8*)(Bs + row * 64 + slot);
            }
            for (int tn = 0; tn < 6; ++tn)
                acc[tn] = __builtin_amdgcn_mfma_f32_16x16x32_bf16(
                    af, bf[tn], acc[tn], 0, 0, 0);
        }
    }

    __syncthreads();
    float* cs = (float*)smem;             // [32][CS_PITCH]
    for (int tn = 0; tn < 6; ++tn) {
        int bd = wave_n * 96 + tn * 16 + cit;
        int o0 = wave_m * 16 + quad * 4;
        f32x4 c = acc[tn];
        for (int r2 = 0; r2 < 4; ++r2)
            cs[(o0 + r2) * CS_PITCH + bd] = c[r2];
    }
    __syncthreads();
    // out[b][o][d]: 64 b x (32 o x 3 d) = 6144 floats; 96-float runs per b.
    for (int it = 0; it < 24; ++it) {
        int flat = it * 256 + tid;        // 0..6143
        int b = flat / 96;
        int w = flat - b * 96;
        int o_l = w / 3, d = w - o_l * 3;
        int og = bm * 32 + o_l;
        if (og < N_IN)
            out[(size_t)b * (N_IN * 3) + (size_t)og * 3 + d] =
                cs[o_l * CS_PITCH + b * 3 + d];
    }
}

extern "C" void kernel_launch(void* const* d_in, const int* in_sizes, int n_in,
                              void* d_out, int out_size, void* d_ws, size_t ws_size,
                              hipStream_t stream) {
    const float* x  = (const float*)d_in[0];
    const float* kw = (const float*)d_in[1];
    const float* qw = (const float*)d_in[2];
    const float* vw = (const float*)d_in[3];
    float* out = (float*)d_out;

    char* w = (char*)d_ws;
    short* qtb  = (short*)(w + 0);                        // 5120*256*2 = 2,621,440
    short* keyT = (short*)(w + 2621440);                  // 256*5120*2 = 2,621,440
    unsigned char* q8 = (unsigned char*)(w + 5242880);    // 5120*256   = 1,310,720
    unsigned char* k8 = (unsigned char*)(w + 6553600);    // 5120*256   = 1,310,720
    float* l1    = (float*)(w + 7864320);                 // 5120*4     = 20,480
    short* vm    = (short*)(w + 7884800);                 // 192*5120*2 = 1,966,080
    float* T32   = (float*)(w + 9850880);                 // 192*256*4  = 196,608
    short* T     = (short*)(w + 10047488);                // 192*256*2  = 98,304
    // total: 10,145,792 bytes

    conv_all<<<dim3(H_DIM / 32, NPAD / 32, 2), dim3(32, 8), 0, stream>>>(
        kw, qw, k8, keyT, q8, qtb, l1);
    gemm_l1<<<dim3(NPAD / 128, NPAD / 128), 256, 0, stream>>>(q8, k8, l1);
    build_vmat<<<dim3(B_SZ, NPAD / 256), 256, 0, stream>>>(x, vw, l1, vm, T32);
    gemm3_f<<<dim3(8, SPLITZ), 256, 0, stream>>>(vm, keyT, T32);
    cvt_T<<<48, 256, 0, stream>>>(T32, T);
    gemm4<<<NPAD / 32, 256, 0, stream>>>(qtb, T, out);
}

// Round 10
// 104.565 us; speedup vs baseline: 1.0035x; 1.0035x over previous
//
#include <hip/hip_runtime.h>
#include <hip/hip_bf16.h>

#define N_IN   5023
#define B_SZ   64
#define H_DIM  256
#define NPAD   5120
#define NBD    192          // B_SZ * 3
#define SPLITZ 40           // gemm3 split-K slices, 128-wide chunks
#define OUT_ELEMS (B_SZ * N_IN * 3)   // 964416

typedef short bf16x8 __attribute__((ext_vector_type(8)));
typedef float f32x4  __attribute__((ext_vector_type(4)));
typedef int   i32x4  __attribute__((ext_vector_type(4)));
typedef int   i32x8  __attribute__((ext_vector_type(8)));

__device__ inline void async_copy16(const void* g, void* l) {
    __builtin_amdgcn_global_load_lds(
        (const __attribute__((address_space(1))) unsigned int*)g,
        (__attribute__((address_space(3))) unsigned int*)l,
        16, 0, 0);
}

__device__ inline unsigned char to_fp8(float v) {
    int p = __builtin_amdgcn_cvt_pk_fp8_f32(v, 0.0f, 0, false);
    return (unsigned char)(p & 0xFF);
}

// ---- conv_all (scalar epilogue — measured best):
//      z=0: key_w[i][h] -> k8 fp8 [5120][256] + keyT bf16 [256][5120]
//      z=1: query_w[h][o] -> q8 fp8 [5120][256] + qtb bf16 [5120][256] (*1/16)
//      q8/k8 hold UNSCALED values (sigma 0.0625, e4m3 normal range).
//      Also zeroes l1 (z=0 blocks). ----
__global__ void conv_all(const float* __restrict__ kw, const float* __restrict__ qw,
                         unsigned char* __restrict__ k8, short* __restrict__ keyT,
                         unsigned char* __restrict__ q8, short* __restrict__ qtb,
                         float* __restrict__ l1) {
    __shared__ float tile[32][33];
    const int hb = blockIdx.x * 32;      // 8 tiles over H
    const int nb = blockIdx.y * 32;      // 160 tiles over NPAD
    const int tx = threadIdx.x;          // 32
    const int ty = threadIdx.y;          // 8
    if (blockIdx.z == 0) {
        // key: read [i][h] coalesced; k8 straight; keyT transposed.
        for (int j = 0; j < 32; j += 8) {
            int i = nb + ty + j;
            int h = hb + tx;
            float v = (i < N_IN) ? kw[(size_t)i * H_DIM + h] : 0.0f;
            tile[ty + j][tx] = v;
            k8[(size_t)i * H_DIM + h] = to_fp8(v);
        }
        __syncthreads();
        __hip_bfloat16* kt = (__hip_bfloat16*)keyT;
        for (int j = 0; j < 32; j += 8) {
            int h = hb + ty + j;
            int i = nb + tx;
            kt[(size_t)h * NPAD + i] = __float2bfloat16(tile[tx][ty + j]);
        }
        if (blockIdx.x == 0 && ty == 0) l1[nb + tx] = 0.0f;
    } else {
        // query: read [h][o] coalesced; q8 + qtb from transposed side.
        for (int j = 0; j < 32; j += 8) {
            int h = hb + ty + j;
            int o = nb + tx;
            tile[ty + j][tx] = (o < N_IN) ? qw[(size_t)h * N_IN + o] : 0.0f;
        }
        __syncthreads();
        __hip_bfloat16* qt = (__hip_bfloat16*)qtb;
        for (int j = 0; j < 32; j += 8) {
            int o = nb + ty + j;
            int h = hb + tx;
            float v = tile[tx][ty + j];
            qt[(size_t)o * H_DIM + h] = __float2bfloat16(v * 0.0625f);
            q8[(size_t)o * H_DIM + h] = to_fp8(v);
        }
    }
}

// ---- GEMM_L1 (MX-fp8, K=128 per MFMA, double-buffered pipeline):
//      l1[i] = sum_o |sum_h q8[o][h]*k8[i][h]| (unscaled by 16^2; folded out
//      downstream). M=N=5120, K=256, tile 128x128. Stage half-0 -> barrier ->
//      ISSUE half-1 loads -> compute half-0 (hides half-1's L2 latency under
//      MFMA) -> barrier -> compute half-1. LDS 64 KB, 2 blocks/CU.
//      XOR-swizzled 16B slots (key = row&7). Unit E8M0 scales (0x7F) make
//      mfma_scale numerically identical to non-scaled fp8 at 2x rate. ----
__launch_bounds__(256)
__global__ void gemm_l1(const unsigned char* __restrict__ q8,
                        const unsigned char* __restrict__ k8,
                        float* __restrict__ l1) {
    __shared__ unsigned char As8[2][128 * 128];   // 32 KB
    __shared__ unsigned char Bs8[2][128 * 128];   // 32 KB
    const int bm = blockIdx.x, bn = blockIdx.y;
    const int tid = threadIdx.x, lane = tid & 63, wid = tid >> 6;
    const int wave_m = wid >> 1, wave_n = wid & 1;
    const int r = lane >> 3;          // 0..7 row within chunk
    const int s = lane & 7;           // 0..7 16B slot
    const int quad = lane >> 4, cit = lane & 15;
    const int xk = cit & 7;           // fragment xor key (= row & 7)

    // ---- stage half 0 ----
    {
        const int koff = ((s ^ r) << 4);
        for (int c = 0; c < 4; ++c) {
            int q = wid * 4 + c;                // 1KB chunk 0..15 (8 rows each)
            int row = q * 8 + r;
            async_copy16(q8 + (size_t)(bm * 128 + row) * H_DIM + koff, As8[0] + q * 1024);
            async_copy16(k8 + (size_t)(bn * 128 + row) * H_DIM + koff, Bs8[0] + q * 1024);
        }
    }

    f32x4 acc[4][4];
    const f32x4 zf = {0.f, 0.f, 0.f, 0.f};
    for (int a = 0; a < 4; ++a)
        for (int b = 0; b < 4; ++b) acc[a][b] = zf;

    // lane's K-slice for the K=128 MFMA: bytes [quad*32, quad*32+32) of its row,
    // i.e. 16B groups g0=2*quad, g1=2*quad+1 (XOR-swizzled in LDS).
    const int g0 = (2 * quad) ^ xk;
    const int g1 = (2 * quad + 1) ^ xk;

    __syncthreads();   // half 0 resident

    // ---- issue half-1 loads (in flight under half-0 compute) ----
    {
        const int koff = 128 + ((s ^ r) << 4);
        for (int c = 0; c < 4; ++c) {
            int q = wid * 4 + c;
            int row = q * 8 + r;
            async_copy16(q8 + (size_t)(bm * 128 + row) * H_DIM + koff, As8[1] + q * 1024);
            async_copy16(k8 + (size_t)(bn * 128 + row) * H_DIM + koff, Bs8[1] + q * 1024);
        }
    }

    // ---- compute half 0 ----
    {
        i32x8 af[4];
        for (int t = 0; t < 4; ++t) {
            const unsigned char* pa = As8[0] + (wave_m * 64 + t * 16 + cit) * 128;
            i32x4 lo = *(const i32x4*)(pa + (g0 << 4));
            i32x4 hi = *(const i32x4*)(pa + (g1 << 4));
            af[t] = __builtin_shufflevector(lo, hi, 0, 1, 2, 3, 4, 5, 6, 7);
        }
        for (int tn = 0; tn < 4; ++tn) {
            const unsigned char* pb = Bs8[0] + (wave_n * 64 + tn * 16 + cit) * 128;
            i32x4 lo = *(const i32x4*)(pb + (g0 << 4));
            i32x4 hi = *(const i32x4*)(pb + (g1 << 4));
            i32x8 bf = __builtin_shufflevector(lo, hi, 0, 1, 2, 3, 4, 5, 6, 7);
            for (int tm = 0; tm < 4; ++tm)
                acc[tm][tn] = __builtin_amdgcn_mfma_scale_f32_16x16x128_f8f6f4(
                    af[tm], bf, acc[tm][tn], 0, 0,
                    0, 0x7F7F7F7F, 0, 0x7F7F7F7F);
        }
    }

    __syncthreads();   // half 1 resident (loads overlapped with compute above)

    // ---- compute half 1 ----
    {
        i32x8 af[4];
        for (int t = 0; t < 4; ++t) {
            const unsigned char* pa = As8[1] + (wave_m * 64 + t * 16 + cit) * 128;
            i32x4 lo = *(const i32x4*)(pa + (g0 << 4));
            i32x4 hi = *(const i32x4*)(pa + (g1 << 4));
            af[t] = __builtin_shufflevector(lo, hi, 0, 1, 2, 3, 4, 5, 6, 7);
        }
        for (int tn = 0; tn < 4; ++tn) {
            const unsigned char* pb = Bs8[1] + (wave_n * 64 + tn * 16 + cit) * 128;
            i32x4 lo = *(const i32x4*)(pb + (g0 << 4));
            i32x4 hi = *(const i32x4*)(pb + (g1 << 4));
            i32x8 bf = __builtin_shufflevector(lo, hi, 0, 1, 2, 3, 4, 5, 6, 7);
            for (int tm = 0; tm < 4; ++tm)
                acc[tm][tn] = __builtin_amdgcn_mfma_scale_f32_16x16x128_f8f6f4(
                    af[tm], bf, acc[tm][tn], 0, 0,
                    0, 0x7F7F7F7F, 0, 0x7F7F7F7F);
        }
    }

    for (int tn = 0; tn < 4; ++tn) {
        int ig = bn * 128 + wave_n * 64 + tn * 16 + cit;   // column i
        float p = 0.0f;
        for (int tm = 0; tm < 4; ++tm) {
            f32x4 c = acc[tm][tn];
            p += fabsf(c.x) + fabsf(c.y) + fabsf(c.z) + fabsf(c.w);
        }
        p += __shfl_xor(p, 16);
        p += __shfl_xor(p, 32);
        if (quad == 0) atomicAdd(&l1[ig], p);
    }
}

// ---- build_vmat: vm[b*3+e][i] = bf16((sum_d x[b,i,d]*vw[e,d]) / max(l1[i]/16,eps))
//      [192][5120] bf16. 1280 blocks; each thread: 4 independent loads, 3 stores,
//      one latency exposure. Pad region i>=N_IN written 0. ----
__launch_bounds__(256)
__global__ void build_vmat(const float* __restrict__ x, const float* __restrict__ vw,
                           const float* __restrict__ l1, short* __restrict__ vm) {
    const int b = blockIdx.x;               // 64
    const int i = blockIdx.y * 256 + threadIdx.x;   // < 5120
    const bool ok = (i < N_IN);
    float x0 = 0.f, x1 = 0.f, x2 = 0.f, rcp = 0.f;
    if (ok) {
        const float* xp = x + ((size_t)b * N_IN + i) * 3;
        x0 = xp[0]; x1 = xp[1]; x2 = xp[2];
        rcp = 1.0f / fmaxf(l1[i] * 0.0625f, 1e-12f);
    }
    __hip_bfloat16* v = (__hip_bfloat16*)vm;
    v[(size_t)(b * 3 + 0) * NPAD + i] = __float2bfloat16((x0 * vw[0] + x1 * vw[1] + x2 * vw[2]) * rcp);
    v[(size_t)(b * 3 + 1) * NPAD + i] = __float2bfloat16((x0 * vw[3] + x1 * vw[4] + x2 * vw[5]) * rcp);
    v[(size_t)(b * 3 + 2) * NPAD + i] = __float2bfloat16((x0 * vw[6] + x1 * vw[7] + x2 * vw[8]) * rcp);
}

// ---- GEMM3 (pure staged GEMM, K=128/block): part2[z][bd][h] =
//      sum_{i in 128-chunk} vm[bd][i] * keyT[h][i]. Grid (8 h-tiles of 32, 40 z)
//      = 320 blocks. Waves 2x2: wave tile 96x16. Both K-halves staged up-front
//      (57 KB LDS, 14 copies/thread in flight, single barrier), 24 MFMAs/wave.
//      XOR-swizzled 16B slots (key = row&7). ----
__launch_bounds__(256)
__global__ void gemm3_f(const short* __restrict__ vm, const short* __restrict__ keyT,
                        float* __restrict__ part2) {
    __shared__ short As[2][NBD * 64];  // 2 x 24,576 B (i-halves)
    __shared__ short Bs[2][32 * 64];   // 2 x 4,096 B
    const int bh = blockIdx.x;         // h tile (8 x 32)
    const int z  = blockIdx.y;         // i chunk (40 x 128)
    const int tid = threadIdx.x, lane = tid & 63, wid = tid >> 6;
    const int wave_m = wid >> 1, wave_n = wid & 1;
    const int rr = lane >> 3, ss = lane & 7;
    const int quad = lane >> 4, cit = lane & 15;
    const int xk = cit & 7;

    for (int hf = 0; hf < 2; ++hf) {
        const int koff = z * 128 + hf * 64 + ((ss ^ rr) << 3);  // pre-swizzled slot
        for (int c = 0; c < 6; ++c) {             // As: 24 chunks per half
            int q = wid * 6 + c;
            int row = q * 8 + rr;                 // bd 0..191
            async_copy16(vm + (size_t)row * NPAD + koff, As[hf] + q * 512);
        }
        {                                          // Bs: 4 chunks per half
            int row = wid * 8 + rr;               // h local 0..31
            async_copy16(keyT + (size_t)(bh * 32 + row) * NPAD + koff, Bs[hf] + wid * 512);
        }
    }
    __syncthreads();

    f32x4 acc[6];
    const f32x4 zf = {0.f, 0.f, 0.f, 0.f};
    for (int a = 0; a < 6; ++a) acc[a] = zf;

    for (int hf = 0; hf < 2; ++hf) {
        for (int kk = 0; kk < 64; kk += 32) {
            bf16x8 af[6], bf;
            int g = (kk >> 3) + quad;
            int slot = (g ^ xk) << 3;             // row&7 == cit&7 for all rows used
            for (int t = 0; t < 6; ++t) {
                int row = wave_m * 96 + t * 16 + cit;
                af[t] = *(const bf16x8*)(As[hf] + row * 64 + slot);
            }
            {
                int row = wave_n * 16 + cit;
                bf = *(const bf16x8*)(Bs[hf] + row * 64 + slot);
            }
            for (int tm = 0; tm < 6; ++tm)
                acc[tm] = __builtin_amdgcn_mfma_f32_16x16x32_bf16(
                    af[tm], bf, acc[tm], 0, 0, 0);
        }
    }

    float* pz = part2 + (size_t)z * (NBD * H_DIM);
    const int h = bh * 32 + wave_n * 16 + cit;
    for (int tm = 0; tm < 6; ++tm) {
        int bd0 = wave_m * 96 + tm * 16 + quad * 4;
        f32x4 c = acc[tm];
        for (int r2 = 0; r2 < 4; ++r2)
            pz[(size_t)(bd0 + r2) * H_DIM + h] = c[r2];
    }
}

// ---- reduce_T: T[bd][h] = bf16(sum_z part2[z][bd][h]) ----
__global__ void reduce_T(const float* __restrict__ part2, short* __restrict__ T) {
    int idx = blockIdx.x * 256 + threadIdx.x;     // < 49152
    float s = 0.0f;
    for (int z = 0; z < SPLITZ; ++z)
        s += part2[(size_t)z * (NBD * H_DIM) + idx];
    ((__hip_bfloat16*)T)[idx] = __float2bfloat16(s);
}

// ---- GEMM4: y[o][bd] = sum_h qt[o][h] * T[bd][h]; out via LDS transpose.
//      M-tile 32 -> 160 blocks. Waves 2x2: wave tile 16x96. XOR-swizzled LDS. ----
#define CS_PITCH 196
__launch_bounds__(256)
__global__ void gemm4(const short* __restrict__ qt, const short* __restrict__ T,
                      float* __restrict__ out) {
    __shared__ __align__(16) char smem[28672];   // staging 28KB / CS 25KB union
    short* As = (short*)smem;                    // 32 x 64 (4 KB, swizzled)
    short* Bs = (short*)(smem + 4096);           // 192 x 64 (24 KB, swizzled)
    const int bm = blockIdx.x;                   // 160
    const int tid = threadIdx.x, lane = tid & 63, wid = tid >> 6;
    const int wave_m = wid >> 1, wave_n = wid & 1;
    const int rr = lane >> 3, ss = lane & 7;
    const int quad = lane >> 4, cit = lane & 15;

    f32x4 acc[6];
    const f32x4 zf = {0.f, 0.f, 0.f, 0.f};
    for (int b = 0; b < 6; ++b) acc[b] = zf;

    for (int kb = 0; kb < H_DIM; kb += 64) {
        __syncthreads();
        const int koff = kb + ((ss ^ (rr & 7)) << 3);
        {   // As: 4 chunks, one per wave
            int row = wid * 8 + rr;              // 0..31
            async_copy16(qt + (size_t)(bm * 32 + row) * H_DIM + koff, As + wid * 512);
        }
        for (int c = 0; c < 6; ++c) {            // Bs: 24 chunks
            int q = wid * 6 + c;
            int row = q * 8 + rr;                // 0..191
            async_copy16(T + (size_t)row * H_DIM + koff, Bs + q * 512);
        }
        __syncthreads();
        for (int kk = 0; kk < 64; kk += 32) {
            bf16x8 af, bf[6];
            int g = (kk >> 3) + quad;
            int slot = (g ^ (cit & 7)) << 3;
            {
                int row = wave_m * 16 + cit;
                af = *(const bf16x8*)(As + row * 64 + slot);
            }
            for (int t = 0; t < 6; ++t) {
                int row = wave_n * 96 + t * 16 + cit;
                bf[t] = *(const bf16x8*)(Bs + row * 64 + slot);
            }
            for (int tn = 0; tn < 6; ++tn)
                acc[tn] = __builtin_amdgcn_mfma_f32_16x16x32_bf16(
                    af, bf[tn], acc[tn], 0, 0, 0);
        }
    }

    __syncthreads();
    float* cs = (float*)smem;             // [32][CS_PITCH]
    for (int tn = 0; tn < 6; ++tn) {
        int bd = wave_n * 96 + tn * 16 + cit;
        int o0 = wave_m * 16 + quad * 4;
        f32x4 c = acc[tn];
        for (int r2 = 0; r2 < 4; ++r2)
            cs[(o0 + r2) * CS_PITCH + bd] = c[r2];
    }
    __syncthreads();
    // out[b][o][d]: 64 b x (32 o x 3 d) = 6144 floats; 96-float runs per b.
    for (int it = 0; it < 24; ++it) {
        int flat = it * 256 + tid;        // 0..6143
        int b = flat / 96;
        int w = flat - b * 96;
        int o_l = w / 3, d = w - o_l * 3;
        int og = bm * 32 + o_l;
        if (og < N_IN)
            out[(size_t)b * (N_IN * 3) + (size_t)og * 3 + d] =
                cs[o_l * CS_PITCH + b * 3 + d];
    }
}

extern "C" void kernel_launch(void* const* d_in, const int* in_sizes, int n_in,
                              void* d_out, int out_size, void* d_ws, size_t ws_size,
                              hipStream_t stream) {
    const float* x  = (const float*)d_in[0];
    const float* kw = (const float*)d_in[1];
    const float* qw = (const float*)d_in[2];
    const float* vw = (const float*)d_in[3];
    float* out = (float*)d_out;

    char* w = (char*)d_ws;
    short* qtb  = (short*)(w + 0);                        // 5120*256*2 = 2,621,440
    short* keyT = (short*)(w + 2621440);                  // 256*5120*2 = 2,621,440
    unsigned char* q8 = (unsigned char*)(w + 5242880);    // 5120*256   = 1,310,720
    unsigned char* k8 = (unsigned char*)(w + 6553600);    // 5120*256   = 1,310,720
    float* l1    = (float*)(w + 7864320);                 // 5120*4     = 20,480
    short* vm    = (short*)(w + 7884800);                 // 192*5120*2 = 1,966,080
    float* part2 = (float*)(w + 9850880);                 // 40*192*256*4 = 7,864,320
    short* T     = (short*)(w + 17715200);                // 192*256*2  = 98,304
    // total: 17,813,504 bytes

    conv_all<<<dim3(H_DIM / 32, NPAD / 32, 2), dim3(32, 8), 0, stream>>>(
        kw, qw, k8, keyT, q8, qtb, l1);
    gemm_l1<<<dim3(NPAD / 128, NPAD / 128), 256, 0, stream>>>(q8, k8, l1);
    build_vmat<<<dim3(B_SZ, NPAD / 256), 256, 0, stream>>>(x, vw, l1, vm);
    gemm3_f<<<dim3(8, SPLITZ), 256, 0, stream>>>(vm, keyT, part2);
    reduce_T<<<(NBD * H_DIM) / 256, 256, 0, stream>>>(part2, T);
    gemm4<<<NPAD / 32, 256, 0, stream>>>(qtb, T, out);
}

// Round 11
// 102.386 us; speedup vs baseline: 1.0248x; 1.0213x over previous
//
#include <hip/hip_runtime.h>
#include <hip/hip_bf16.h>

#define N_IN   5023
#define B_SZ   64
#define H_DIM  256
#define NPAD   5120
#define NBD    192          // B_SZ * 3
#define SPLITZ 40           // gemm3 split-K slices, 128-wide chunks
#define OUT_ELEMS (B_SZ * N_IN * 3)   // 964416

typedef short bf16x8 __attribute__((ext_vector_type(8)));
typedef float f32x4  __attribute__((ext_vector_type(4)));
typedef int   i32x4  __attribute__((ext_vector_type(4)));
typedef int   i32x8  __attribute__((ext_vector_type(8)));

__device__ inline void async_copy16(const void* g, void* l) {
    __builtin_amdgcn_global_load_lds(
        (const __attribute__((address_space(1))) unsigned int*)g,
        (__attribute__((address_space(3))) unsigned int*)l,
        16, 0, 0);
}

__device__ inline unsigned char to_fp8(float v) {
    int p = __builtin_amdgcn_cvt_pk_fp8_f32(v, 0.0f, 0, false);
    return (unsigned char)(p & 0xFF);
}

// ---- conv_all (scalar epilogue — measured best):
//      z=0: key_w[i][h] -> k8 fp8 [5120][256] + keyT bf16 [256][5120]
//      z=1: query_w[h][o] -> q8 fp8 [5120][256] + qtb bf16 [5120][256] (*1/16)
//      q8/k8 hold UNSCALED values (sigma 0.0625, e4m3 normal range).
//      Also zeroes l1 (z=0 blocks). ----
__global__ void conv_all(const float* __restrict__ kw, const float* __restrict__ qw,
                         unsigned char* __restrict__ k8, short* __restrict__ keyT,
                         unsigned char* __restrict__ q8, short* __restrict__ qtb,
                         float* __restrict__ l1) {
    __shared__ float tile[32][33];
    const int hb = blockIdx.x * 32;      // 8 tiles over H
    const int nb = blockIdx.y * 32;      // 160 tiles over NPAD
    const int tx = threadIdx.x;          // 32
    const int ty = threadIdx.y;          // 8
    if (blockIdx.z == 0) {
        // key: read [i][h] coalesced; k8 straight; keyT transposed.
        for (int j = 0; j < 32; j += 8) {
            int i = nb + ty + j;
            int h = hb + tx;
            float v = (i < N_IN) ? kw[(size_t)i * H_DIM + h] : 0.0f;
            tile[ty + j][tx] = v;
            k8[(size_t)i * H_DIM + h] = to_fp8(v);
        }
        __syncthreads();
        __hip_bfloat16* kt = (__hip_bfloat16*)keyT;
        for (int j = 0; j < 32; j += 8) {
            int h = hb + ty + j;
            int i = nb + tx;
            kt[(size_t)h * NPAD + i] = __float2bfloat16(tile[tx][ty + j]);
        }
        if (blockIdx.x == 0 && ty == 0) l1[nb + tx] = 0.0f;
    } else {
        // query: read [h][o] coalesced; q8 + qtb from transposed side.
        for (int j = 0; j < 32; j += 8) {
            int h = hb + ty + j;
            int o = nb + tx;
            tile[ty + j][tx] = (o < N_IN) ? qw[(size_t)h * N_IN + o] : 0.0f;
        }
        __syncthreads();
        __hip_bfloat16* qt = (__hip_bfloat16*)qtb;
        for (int j = 0; j < 32; j += 8) {
            int o = nb + ty + j;
            int h = hb + tx;
            float v = tile[tx][ty + j];
            qt[(size_t)o * H_DIM + h] = __float2bfloat16(v * 0.0625f);
            q8[(size_t)o * H_DIM + h] = to_fp8(v);
        }
    }
}

// ---- GEMM_L1 (MX-fp8, K=128 per MFMA): l1[i] = sum_o |sum_h q8[o][h]*k8[i][h]|
//      (unscaled by 16^2; folded out downstream). M=N=5120, K=256, tile 128x128,
//      BK=128 (2 rounds), LDS 2x16KB, XOR-swizzled 16B slots (key = row&7).
//      mfma_scale_f32_16x16x128_f8f6f4 with unit E8M0 scales (0x7F bytes) is
//      numerically identical to the non-scaled fp8 path at 2x the rate.
//      [Measured best of 4 variants: 2-stage 32KB > dbuf 64KB > 1-stage 64KB.] ----
__launch_bounds__(256)
__global__ void gemm_l1(const unsigned char* __restrict__ q8,
                        const unsigned char* __restrict__ k8,
                        float* __restrict__ l1) {
    __shared__ unsigned char As8[128 * 128];   // 16 KB
    __shared__ unsigned char Bs8[128 * 128];   // 16 KB
    const int bm = blockIdx.x, bn = blockIdx.y;
    const int tid = threadIdx.x, lane = tid & 63, wid = tid >> 6;
    const int wave_m = wid >> 1, wave_n = wid & 1;
    const int r = lane >> 3;          // 0..7 row within chunk
    const int s = lane & 7;           // 0..7 16B slot
    const int quad = lane >> 4, cit = lane & 15;
    const int xk = cit & 7;           // fragment xor key (= row & 7)

    f32x4 acc[4][4];
    const f32x4 zf = {0.f, 0.f, 0.f, 0.f};
    for (int a = 0; a < 4; ++a)
        for (int b = 0; b < 4; ++b) acc[a][b] = zf;

    // lane's K-slice for the K=128 MFMA: bytes [quad*32, quad*32+32) of its row,
    // i.e. 16B groups g0=2*quad, g1=2*quad+1 (XOR-swizzled in LDS).
    const int g0 = (2 * quad) ^ xk;
    const int g1 = (2 * quad + 1) ^ xk;

    for (int kb = 0; kb < H_DIM; kb += 128) {
        __syncthreads();
        const int koff = kb + ((s ^ r) << 4);   // swizzled global k-group
        for (int c = 0; c < 4; ++c) {
            int q = wid * 4 + c;                // 1KB chunk 0..15 (8 rows each)
            int row = q * 8 + r;
            async_copy16(q8 + (size_t)(bm * 128 + row) * H_DIM + koff, As8 + q * 1024);
            async_copy16(k8 + (size_t)(bn * 128 + row) * H_DIM + koff, Bs8 + q * 1024);
        }
        __syncthreads();
        // A fragments: 4 rows of 32B each (2 x ds_read_b128)
        i32x8 af[4];
        for (int t = 0; t < 4; ++t) {
            const unsigned char* pa = As8 + (wave_m * 64 + t * 16 + cit) * 128;
            i32x4 lo = *(const i32x4*)(pa + (g0 << 4));
            i32x4 hi = *(const i32x4*)(pa + (g1 << 4));
            af[t] = __builtin_shufflevector(lo, hi, 0, 1, 2, 3, 4, 5, 6, 7);
        }
        // B fragment per output column, then 4 MFMAs down the column
        for (int tn = 0; tn < 4; ++tn) {
            const unsigned char* pb = Bs8 + (wave_n * 64 + tn * 16 + cit) * 128;
            i32x4 lo = *(const i32x4*)(pb + (g0 << 4));
            i32x4 hi = *(const i32x4*)(pb + (g1 << 4));
            i32x8 bf = __builtin_shufflevector(lo, hi, 0, 1, 2, 3, 4, 5, 6, 7);
            for (int tm = 0; tm < 4; ++tm)
                acc[tm][tn] = __builtin_amdgcn_mfma_scale_f32_16x16x128_f8f6f4(
                    af[tm], bf, acc[tm][tn], 0, 0,   // cbsz=fp8(e4m3), blgp=fp8(e4m3)
                    0, 0x7F7F7F7F,                   // A scales: E8M0 127 -> 2^0
                    0, 0x7F7F7F7F);                  // B scales: E8M0 127 -> 2^0
        }
    }

    for (int tn = 0; tn < 4; ++tn) {
        int ig = bn * 128 + wave_n * 64 + tn * 16 + cit;   // column i
        float p = 0.0f;
        for (int tm = 0; tm < 4; ++tm) {
            f32x4 c = acc[tm][tn];
            p += fabsf(c.x) + fabsf(c.y) + fabsf(c.z) + fabsf(c.w);
        }
        p += __shfl_xor(p, 16);
        p += __shfl_xor(p, 32);
        if (quad == 0) atomicAdd(&l1[ig], p);
    }
}

// ---- build_vmat: vm[b*3+e][i] = bf16((sum_d x[b,i,d]*vw[e,d]) / max(l1[i]/16,eps))
//      [192][5120] bf16. 1280 blocks; each thread: 4 independent loads, 3 stores,
//      one latency exposure. Pad region i>=N_IN written 0. ----
__launch_bounds__(256)
__global__ void build_vmat(const float* __restrict__ x, const float* __restrict__ vw,
                           const float* __restrict__ l1, short* __restrict__ vm) {
    const int b = blockIdx.x;               // 64
    const int i = blockIdx.y * 256 + threadIdx.x;   // < 5120
    const bool ok = (i < N_IN);
    float x0 = 0.f, x1 = 0.f, x2 = 0.f, rcp = 0.f;
    if (ok) {
        const float* xp = x + ((size_t)b * N_IN + i) * 3;
        x0 = xp[0]; x1 = xp[1]; x2 = xp[2];
        rcp = 1.0f / fmaxf(l1[i] * 0.0625f, 1e-12f);
    }
    __hip_bfloat16* v = (__hip_bfloat16*)vm;
    v[(size_t)(b * 3 + 0) * NPAD + i] = __float2bfloat16((x0 * vw[0] + x1 * vw[1] + x2 * vw[2]) * rcp);
    v[(size_t)(b * 3 + 1) * NPAD + i] = __float2bfloat16((x0 * vw[3] + x1 * vw[4] + x2 * vw[5]) * rcp);
    v[(size_t)(b * 3 + 2) * NPAD + i] = __float2bfloat16((x0 * vw[6] + x1 * vw[7] + x2 * vw[8]) * rcp);
}

// ---- GEMM3 (pure staged GEMM, K=128/block): part2[z][bd][h] =
//      sum_{i in 128-chunk} vm[bd][i] * keyT[h][i]. Grid (8 h-tiles of 32, 40 z)
//      = 320 blocks. Waves 2x2: wave tile 96x16. Both K-halves staged up-front
//      (57 KB LDS, 14 copies/thread in flight, single barrier), 24 MFMAs/wave.
//      XOR-swizzled 16B slots (key = row&7). ----
__launch_bounds__(256)
__global__ void gemm3_f(const short* __restrict__ vm, const short* __restrict__ keyT,
                        float* __restrict__ part2) {
    __shared__ short As[2][NBD * 64];  // 2 x 24,576 B (i-halves)
    __shared__ short Bs[2][32 * 64];   // 2 x 4,096 B
    const int bh = blockIdx.x;         // h tile (8 x 32)
    const int z  = blockIdx.y;         // i chunk (40 x 128)
    const int tid = threadIdx.x, lane = tid & 63, wid = tid >> 6;
    const int wave_m = wid >> 1, wave_n = wid & 1;
    const int rr = lane >> 3, ss = lane & 7;
    const int quad = lane >> 4, cit = lane & 15;
    const int xk = cit & 7;

    for (int hf = 0; hf < 2; ++hf) {
        const int koff = z * 128 + hf * 64 + ((ss ^ rr) << 3);  // pre-swizzled slot
        for (int c = 0; c < 6; ++c) {             // As: 24 chunks per half
            int q = wid * 6 + c;
            int row = q * 8 + rr;                 // bd 0..191
            async_copy16(vm + (size_t)row * NPAD + koff, As[hf] + q * 512);
        }
        {                                          // Bs: 4 chunks per half
            int row = wid * 8 + rr;               // h local 0..31
            async_copy16(keyT + (size_t)(bh * 32 + row) * NPAD + koff, Bs[hf] + wid * 512);
        }
    }
    __syncthreads();

    f32x4 acc[6];
    const f32x4 zf = {0.f, 0.f, 0.f, 0.f};
    for (int a = 0; a < 6; ++a) acc[a] = zf;

    for (int hf = 0; hf < 2; ++hf) {
        for (int kk = 0; kk < 64; kk += 32) {
            bf16x8 af[6], bf;
            int g = (kk >> 3) + quad;
            int slot = (g ^ xk) << 3;             // row&7 == cit&7 for all rows used
            for (int t = 0; t < 6; ++t) {
                int row = wave_m * 96 + t * 16 + cit;
                af[t] = *(const bf16x8*)(As[hf] + row * 64 + slot);
            }
            {
                int row = wave_n * 16 + cit;
                bf = *(const bf16x8*)(Bs[hf] + row * 64 + slot);
            }
            for (int tm = 0; tm < 6; ++tm)
                acc[tm] = __builtin_amdgcn_mfma_f32_16x16x32_bf16(
                    af[tm], bf, acc[tm], 0, 0, 0);
        }
    }

    float* pz = part2 + (size_t)z * (NBD * H_DIM);
    const int h = bh * 32 + wave_n * 16 + cit;
    for (int tm = 0; tm < 6; ++tm) {
        int bd0 = wave_m * 96 + tm * 16 + quad * 4;
        f32x4 c = acc[tm];
        for (int r2 = 0; r2 < 4; ++r2)
            pz[(size_t)(bd0 + r2) * H_DIM + h] = c[r2];
    }
}

// ---- reduce_T: T[bd][h] = bf16(sum_z part2[z][bd][h]) ----
__global__ void reduce_T(const float* __restrict__ part2, short* __restrict__ T) {
    int idx = blockIdx.x * 256 + threadIdx.x;     // < 49152
    float s = 0.0f;
    for (int z = 0; z < SPLITZ; ++z)
        s += part2[(size_t)z * (NBD * H_DIM) + idx];
    ((__hip_bfloat16*)T)[idx] = __float2bfloat16(s);
}

// ---- GEMM4 (single-stage K=256): y[o][bd] = sum_h qt[o][h] * T[bd][h].
//      160 blocks <= 256 CUs -> 1 block/CU regardless of LDS, so staging the
//      whole K range up front (As 16KB + Bs 96KB = 112KB, 28 copies/thread all
//      in flight, ONE barrier) costs no occupancy and removes 3 of 4 exposed
//      stage-drain serializations. Waves 2x2: wave tile 16x96. XOR-swizzled.
//      Out via LDS transpose (CS reuses the same smem). ----
#define CS_PITCH 196
__launch_bounds__(256)
__global__ void gemm4(const short* __restrict__ qt, const short* __restrict__ T,
                      float* __restrict__ out) {
    __shared__ __align__(16) char smem[114688];  // As 16KB | Bs 96KB ; CS 25KB union
    short* As = (short*)smem;                    // 4 panels x 32 x 64 (swizzled)
    short* Bs = (short*)(smem + 16384);          // 4 panels x 192 x 64 (swizzled)
    const int bm = blockIdx.x;                   // 160
    const int tid = threadIdx.x, lane = tid & 63, wid = tid >> 6;
    const int wave_m = wid >> 1, wave_n = wid & 1;
    const int rr = lane >> 3, ss = lane & 7;
    const int quad = lane >> 4, cit = lane & 15;

    // ---- stage ALL of K=256: 4 panels of 64 cols each ----
    for (int p = 0; p < 4; ++p) {
        const int koff = p * 64 + ((ss ^ (rr & 7)) << 3);
        {   // As panel p: 4 chunks, one per wave
            int row = wid * 8 + rr;              // 0..31
            async_copy16(qt + (size_t)(bm * 32 + row) * H_DIM + koff,
                         As + p * 2048 + wid * 512);
        }
        for (int c = 0; c < 6; ++c) {            // Bs panel p: 24 chunks
            int q = wid * 6 + c;
            int row = q * 8 + rr;                // 0..191
            async_copy16(T + (size_t)row * H_DIM + koff,
                         Bs + p * 12288 + q * 512);
        }
    }

    f32x4 acc[6];
    const f32x4 zf = {0.f, 0.f, 0.f, 0.f};
    for (int b = 0; b < 6; ++b) acc[b] = zf;

    __syncthreads();   // single drain for all 28 copies/thread

    for (int p = 0; p < 4; ++p) {
        const short* Ap = As + p * 2048;
        const short* Bp = Bs + p * 12288;
        for (int kk = 0; kk < 64; kk += 32) {
            bf16x8 af, bf[6];
            int g = (kk >> 3) + quad;
            int slot = (g ^ (cit & 7)) << 3;
            {
                int row = wave_m * 16 + cit;
                af = *(const bf16x8*)(Ap + row * 64 + slot);
            }
            for (int t = 0; t < 6; ++t) {
                int row = wave_n * 96 + t * 16 + cit;
                bf[t] = *(const bf16x8*)(Bp + row * 64 + slot);
            }
            for (int tn = 0; tn < 6; ++tn)
                acc[tn] = __builtin_amdgcn_mfma_f32_16x16x32_bf16(
                    af, bf[tn], acc[tn], 0, 0, 0);
        }
    }

    __syncthreads();
    float* cs = (float*)smem;             // [32][CS_PITCH]
    for (int tn = 0; tn < 6; ++tn) {
        int bd = wave_n * 96 + tn * 16 + cit;
        int o0 = wave_m * 16 + quad * 4;
        f32x4 c = acc[tn];
        for (int r2 = 0; r2 < 4; ++r2)
            cs[(o0 + r2) * CS_PITCH + bd] = c[r2];
    }
    __syncthreads();
    // out[b][o][d]: 64 b x (32 o x 3 d) = 6144 floats; 96-float runs per b.
    for (int it = 0; it < 24; ++it) {
        int flat = it * 256 + tid;        // 0..6143
        int b = flat / 96;
        int w = flat - b * 96;
        int o_l = w / 3, d = w - o_l * 3;
        int og = bm * 32 + o_l;
        if (og < N_IN)
            out[(size_t)b * (N_IN * 3) + (size_t)og * 3 + d] =
                cs[o_l * CS_PITCH + b * 3 + d];
    }
}

extern "C" void kernel_launch(void* const* d_in, const int* in_sizes, int n_in,
                              void* d_out, int out_size, void* d_ws, size_t ws_size,
                              hipStream_t stream) {
    const float* x  = (const float*)d_in[0];
    const float* kw = (const float*)d_in[1];
    const float* qw = (const float*)d_in[2];
    const float* vw = (const float*)d_in[3];
    float* out = (float*)d_out;

    char* w = (char*)d_ws;
    short* qtb  = (short*)(w + 0);                        // 5120*256*2 = 2,621,440
    short* keyT = (short*)(w + 2621440);                  // 256*5120*2 = 2,621,440
    unsigned char* q8 = (unsigned char*)(w + 5242880);    // 5120*256   = 1,310,720
    unsigned char* k8 = (unsigned char*)(w + 6553600);    // 5120*256   = 1,310,720
    float* l1    = (float*)(w + 7864320);                 // 5120*4     = 20,480
    short* vm    = (short*)(w + 7884800);                 // 192*5120*2 = 1,966,080
    float* part2 = (float*)(w + 9850880);                 // 40*192*256*4 = 7,864,320
    short* T     = (short*)(w + 17715200);                // 192*256*2  = 98,304
    // total: 17,813,504 bytes

    conv_all<<<dim3(H_DIM / 32, NPAD / 32, 2), dim3(32, 8), 0, stream>>>(
        kw, qw, k8, keyT, q8, qtb, l1);
    gemm_l1<<<dim3(NPAD / 128, NPAD / 128), 256, 0, stream>>>(q8, k8, l1);
    build_vmat<<<dim3(B_SZ, NPAD / 256), 256, 0, stream>>>(x, vw, l1, vm);
    gemm3_f<<<dim3(8, SPLITZ), 256, 0, stream>>>(vm, keyT, part2);
    reduce_T<<<(NBD * H_DIM) / 256, 256, 0, stream>>>(part2, T);
    gemm4<<<NPAD / 32, 256, 0, stream>>>(qtb, T, out);
}